// Round 1
// baseline (497.815 us; speedup 1.0000x reference)
//
#include <hip/hip_runtime.h>
#include <hip/hip_bf16.h>
#include <stdint.h>

#define D_MODEL 1024
#define S_LEN   4096
#define BATCH   4
#define HEADS   16
#define DEPTH   64
#define ROWS    (BATCH*S_LEN)   // 16384
#define EPS_K_F 1e-6f
#define EPS_LN_F 1e-6f

typedef __attribute__((ext_vector_type(8))) short short8;
typedef __attribute__((ext_vector_type(4))) float f32x4;

__device__ __forceinline__ unsigned short f2bf(float f) {
  union { float f; unsigned u; } x; x.f = f;
  unsigned r = x.u + 0x7FFF + ((x.u >> 16) & 1);
  return (unsigned short)(r >> 16);
}
__device__ __forceinline__ float bf2f(unsigned short b) {
  union { unsigned u; float f; } x; x.u = ((unsigned)b) << 16;
  return x.f;
}
__device__ __forceinline__ void gload16(const void* g, void* l) {
  __builtin_amdgcn_global_load_lds(
      (const __attribute__((address_space(1))) void*)g,
      (__attribute__((address_space(3))) void*)l, 16, 0, 0);
}

// ---------------- f32 -> bf16 convert ----------------
__global__ __launch_bounds__(256) void cvt_f32_bf16_k(
    const float* __restrict__ in, unsigned short* __restrict__ out, int n4) {
  int i = blockIdx.x * 256 + threadIdx.x;
  if (i < n4) {
    float4 v = ((const float4*)in)[i];
    ushort4 o;
    o.x = f2bf(v.x); o.y = f2bf(v.y); o.z = f2bf(v.z); o.w = f2bf(v.w);
    ((ushort4*)out)[i] = o;
  }
}

// ---------------- weight transpose + convert: W[K,N] f32 -> Wt[N,K] bf16 ----
__global__ __launch_bounds__(256) void wtrans_k(
    const float* __restrict__ W, unsigned short* __restrict__ Wt) {
  __shared__ float tile[32][33];
  int n0 = blockIdx.x * 32, k0 = blockIdx.y * 32;
  int tx = threadIdx.x & 31, ty = threadIdx.x >> 5;
  #pragma unroll
  for (int i = 0; i < 32; i += 8)
    tile[ty + i][tx] = W[(size_t)(k0 + ty + i) * D_MODEL + n0 + tx];
  __syncthreads();
  #pragma unroll
  for (int i = 0; i < 32; i += 8)
    Wt[(size_t)(n0 + ty + i) * D_MODEL + k0 + tx] = f2bf(tile[tx][ty + i]);
}

// ---------------- bf16 GEMM: A[M,K] @ Bt[N,K]^T -> C[M,N] f32 (+bias) -------
__global__ __launch_bounds__(256) void gemm_bt_k(
    const unsigned short* __restrict__ A,
    const unsigned short* __restrict__ Bt,
    float* __restrict__ C,
    const float* __restrict__ bias,
    int M, int N, int K) {
  __shared__ unsigned short Al[128 * 64];
  __shared__ unsigned short Bl[128 * 64];
  int t = threadIdx.x;
  int lane = t & 63, wid = t >> 6;
  int wr = wid >> 1, wc = wid & 1;
  int l15 = lane & 15, lhi = lane >> 4;
  size_t m0 = (size_t)blockIdx.y * 128, n0 = (size_t)blockIdx.x * 128;
  f32x4 acc[4][4] = {};

  for (int k0 = 0; k0 < K; k0 += 64) {
    #pragma unroll
    for (int i = 0; i < 4; ++i) {
      int cid = i * 256 + t;
      int r = cid >> 3, c8 = cid & 7;
      gload16(A  + (m0 + r) * (size_t)K + k0 + c8 * 8, &Al[cid * 8]);
      gload16(Bt + (n0 + r) * (size_t)K + k0 + c8 * 8, &Bl[cid * 8]);
    }
    asm volatile("s_waitcnt vmcnt(0)" ::: "memory");
    __syncthreads();
    #pragma unroll
    for (int kk = 0; kk < 2; ++kk) {
      short8 af[4], bfr[4];
      #pragma unroll
      for (int m = 0; m < 4; ++m)
        af[m] = *(const short8*)&Al[(wr * 64 + m * 16 + l15) * 64 + kk * 32 + lhi * 8];
      #pragma unroll
      for (int n = 0; n < 4; ++n)
        bfr[n] = *(const short8*)&Bl[(wc * 64 + n * 16 + l15) * 64 + kk * 32 + lhi * 8];
      #pragma unroll
      for (int m = 0; m < 4; ++m)
        #pragma unroll
        for (int n = 0; n < 4; ++n)
          acc[m][n] = __builtin_amdgcn_mfma_f32_16x16x32_bf16(af[m], bfr[n], acc[m][n], 0, 0, 0);
    }
    __syncthreads();
  }
  float bv[4];
  #pragma unroll
  for (int n = 0; n < 4; ++n) {
    int col = (int)n0 + wc * 64 + n * 16 + l15;
    bv[n] = bias ? bias[col] : 0.f;
  }
  #pragma unroll
  for (int m = 0; m < 4; ++m)
    #pragma unroll
    for (int j = 0; j < 4; ++j) {
      size_t row = m0 + wr * 64 + m * 16 + lhi * 4 + j;
      #pragma unroll
      for (int n = 0; n < 4; ++n) {
        int col = (int)n0 + wc * 64 + n * 16 + l15;
        C[row * N + col] = acc[m][n][j] + bv[n];
      }
    }
}

// ---------------- LN + activation -> bf16 -----------------------------------
// mode 0: relu(ln)+eps ; mode 1: (relu(ln)+eps)*mask ; mode 2: ln*mask
__global__ __launch_bounds__(256) void ln_act_k(
    const float* __restrict__ Y, const float* __restrict__ gamma,
    const float* __restrict__ beta, const float* __restrict__ mask,
    unsigned short* __restrict__ out, int mode) {
  int row = blockIdx.x;
  int t = threadIdx.x;
  const float* y = Y + (size_t)row * D_MODEL;
  float4 v = ((const float4*)y)[t];
  float av[4] = {v.x, v.y, v.z, v.w};
  float s = av[0] + av[1] + av[2] + av[3];
  float s2 = av[0]*av[0] + av[1]*av[1] + av[2]*av[2] + av[3]*av[3];
  #pragma unroll
  for (int o = 32; o > 0; o >>= 1) { s += __shfl_xor(s, o); s2 += __shfl_xor(s2, o); }
  __shared__ float red[8];
  int wid = t >> 6, lane = t & 63;
  if (lane == 0) { red[wid] = s; red[4 + wid] = s2; }
  __syncthreads();
  s  = red[0] + red[1] + red[2] + red[3];
  s2 = red[4] + red[5] + red[6] + red[7];
  float mean = s * (1.f / D_MODEL);
  float var = s2 * (1.f / D_MODEL) - mean * mean;
  float rstd = rsqrtf(var + EPS_LN_F);
  float mk = (mode > 0) ? mask[row] : 1.f;
  float4 gv = ((const float4*)gamma)[t];
  float4 bv = ((const float4*)beta)[t];
  float g4[4] = {gv.x, gv.y, gv.z, gv.w};
  float b4[4] = {bv.x, bv.y, bv.z, bv.w};
  unsigned short ov[4];
  #pragma unroll
  for (int j = 0; j < 4; ++j) {
    float ln = (av[j] - mean) * rstd * g4[j] + b4[j];
    if (mode == 0)      ln = fmaxf(ln, 0.f) + EPS_K_F;
    else if (mode == 1) ln = (fmaxf(ln, 0.f) + EPS_K_F) * mk;
    else                ln = ln * mk;
    ov[j] = f2bf(ln);
  }
  ushort4 o; o.x = ov[0]; o.y = ov[1]; o.z = ov[2]; o.w = ov[3];
  ((ushort4*)(out + (size_t)row * D_MODEL))[t] = o;
}

// ---------------- final LayerNorm (in-place, f32) ---------------------------
__global__ __launch_bounds__(256) void ln_final_k(
    float* __restrict__ Y, const float* __restrict__ gamma,
    const float* __restrict__ beta) {
  int row = blockIdx.x;
  int t = threadIdx.x;
  float* y = Y + (size_t)row * D_MODEL;
  float4 v = ((const float4*)y)[t];
  float av[4] = {v.x, v.y, v.z, v.w};
  float s = av[0] + av[1] + av[2] + av[3];
  float s2 = av[0]*av[0] + av[1]*av[1] + av[2]*av[2] + av[3]*av[3];
  #pragma unroll
  for (int o = 32; o > 0; o >>= 1) { s += __shfl_xor(s, o); s2 += __shfl_xor(s2, o); }
  __shared__ float red[8];
  int wid = t >> 6, lane = t & 63;
  if (lane == 0) { red[wid] = s; red[4 + wid] = s2; }
  __syncthreads();
  s  = red[0] + red[1] + red[2] + red[3];
  s2 = red[4] + red[5] + red[6] + red[7];
  float mean = s * (1.f / D_MODEL);
  float var = s2 * (1.f / D_MODEL) - mean * mean;
  float rstd = rsqrtf(var + EPS_LN_F);
  float4 gv = ((const float4*)gamma)[t];
  float4 bv = ((const float4*)beta)[t];
  float4 w;
  w.x = (av[0] - mean) * rstd * gv.x + bv.x;
  w.y = (av[1] - mean) * rstd * gv.y + bv.y;
  w.z = (av[2] - mean) * rstd * gv.z + bv.z;
  w.w = (av[3] - mean) * rstd * gv.w + bv.w;
  __syncthreads();
  ((float4*)y)[t] = w;
}

// ---------------- KV partials: per (b,h,chunk): sum_n k'[n,d]*v[n,e] --------
__global__ __launch_bounds__(256) void kv_part_k(
    const unsigned short* __restrict__ Kp, const unsigned short* __restrict__ Vp,
    float* __restrict__ part, float* __restrict__ kspart) {
  int bh = blockIdx.y, chunk = blockIdx.x;
  int b = bh >> 4, h = bh & 15;
  int t = threadIdx.x;
  __shared__ unsigned short Kl[16][64];
  __shared__ unsigned short Vl[16][64];
  int e = t & 63, dg = t >> 6;
  float acc[16];
  #pragma unroll
  for (int i = 0; i < 16; ++i) acc[i] = 0.f;
  float ks = 0.f;
  size_t rowbase = (size_t)b * S_LEN + (size_t)chunk * 512;
  int lr = t >> 4, lc = (t & 15) * 4;
  for (int n0 = 0; n0 < 512; n0 += 16) {
    size_t g = (rowbase + n0 + lr) * D_MODEL + h * DEPTH + lc;
    *(ushort4*)&Kl[lr][lc] = *(const ushort4*)&Kp[g];
    *(ushort4*)&Vl[lr][lc] = *(const ushort4*)&Vp[g];
    __syncthreads();
    #pragma unroll
    for (int r = 0; r < 16; ++r) {
      float ve = bf2f(Vl[r][e]);
      short8 k0 = *(const short8*)&Kl[r][dg * 16];
      short8 k1 = *(const short8*)&Kl[r][dg * 16 + 8];
      #pragma unroll
      for (int i = 0; i < 8; ++i) {
        acc[i]     += bf2f((unsigned short)k0[i]) * ve;
        acc[8 + i] += bf2f((unsigned short)k1[i]) * ve;
      }
    }
    if (t < 64) {
      #pragma unroll
      for (int r = 0; r < 16; ++r) ks += bf2f(Kl[r][t]);
    }
    __syncthreads();
  }
  float* pp = part + ((size_t)bh * 8 + chunk) * 4096;
  #pragma unroll
  for (int i = 0; i < 16; ++i)
    pp[(dg * 16 + i) * 64 + e] = acc[i];
  if (t < 64) kspart[((size_t)bh * 8 + chunk) * 64 + t] = ks;
}

// ---------------- KV reduce -> KV^T bf16 ([e][d]) + ksum f32 ----------------
__global__ __launch_bounds__(256) void kv_reduce_k(
    const float* __restrict__ part, const float* __restrict__ kspart,
    unsigned short* __restrict__ KVT, float* __restrict__ ksum) {
  int bh = blockIdx.x, t = threadIdx.x;
  for (int idx = t; idx < 4096; idx += 256) {
    int d = idx >> 6, e = idx & 63;
    float s = 0.f;
    #pragma unroll
    for (int c = 0; c < 8; ++c)
      s += part[((size_t)bh * 8 + c) * 4096 + d * 64 + e];
    KVT[(size_t)bh * 4096 + e * 64 + d] = f2bf(s);
  }
  if (t < 64) {
    float s = 0.f;
    #pragma unroll
    for (int c = 0; c < 8; ++c) s += kspart[((size_t)bh * 8 + c) * 64 + t];
    ksum[bh * 64 + t] = s;
  }
}

// ---------------- att = (q' @ KV) * z, written in the reference's reshape ---
__global__ __launch_bounds__(256) void att_k(
    const unsigned short* __restrict__ Qp, const unsigned short* __restrict__ KVT,
    const float* __restrict__ ksum, unsigned short* __restrict__ att) {
  __shared__ unsigned short Ql[128 * 64];
  __shared__ unsigned short Kl[64 * 64];
  __shared__ float ksl[64];
  __shared__ float zl[128];
  int bh = blockIdx.y;
  int b = bh >> 4, h = bh & 15;
  int r0 = blockIdx.x * 128;
  int t = threadIdx.x, lane = t & 63, wid = t >> 6;
  int l15 = lane & 15, lhi = lane >> 4;
  #pragma unroll
  for (int i = 0; i < 4; ++i) {
    int cid = i * 256 + t;
    int r = cid >> 3, c8 = cid & 7;
    gload16(Qp + ((size_t)(b * S_LEN + r0 + r)) * D_MODEL + h * DEPTH + c8 * 8,
            &Ql[cid * 8]);
  }
  #pragma unroll
  for (int i = 0; i < 2; ++i) {
    int cid = i * 256 + t;
    gload16(KVT + (size_t)bh * 4096 + cid * 8, &Kl[cid * 8]);
  }
  if (t < 64) ksl[t] = ksum[bh * 64 + t];
  asm volatile("s_waitcnt vmcnt(0)" ::: "memory");
  __syncthreads();
  {
    int r = t >> 1, half = t & 1;
    float s = 0.f;
    #pragma unroll
    for (int j = 0; j < 32; ++j)
      s += bf2f(Ql[r * 64 + half * 32 + j]) * ksl[half * 32 + j];
    s += __shfl_xor(s, 1);
    if (half == 0) zl[r] = 1.f / (s + EPS_K_F);
  }
  __syncthreads();
  f32x4 acc[2][4] = {};
  #pragma unroll
  for (int kk = 0; kk < 2; ++kk) {
    short8 af[2], bfr[4];
    #pragma unroll
    for (int m = 0; m < 2; ++m)
      af[m] = *(const short8*)&Ql[(wid * 32 + m * 16 + l15) * 64 + kk * 32 + lhi * 8];
    #pragma unroll
    for (int n = 0; n < 4; ++n)
      bfr[n] = *(const short8*)&Kl[(n * 16 + l15) * 64 + kk * 32 + lhi * 8];
    #pragma unroll
    for (int m = 0; m < 2; ++m)
      #pragma unroll
      for (int n = 0; n < 4; ++n)
        acc[m][n] = __builtin_amdgcn_mfma_f32_16x16x32_bf16(af[m], bfr[n], acc[m][n], 0, 0, 0);
  }
  // reference reshape: att_flat[b, h*256 + n/16, (n%16)*64 + e]
  #pragma unroll
  for (int m = 0; m < 2; ++m)
    #pragma unroll
    for (int j = 0; j < 4; ++j) {
      int rl = wid * 32 + m * 16 + lhi * 4 + j;
      int n = r0 + rl;
      float z = zl[rl];
      #pragma unroll
      for (int nf = 0; nf < 4; ++nf) {
        int ee = nf * 16 + l15;
        size_t orow = (size_t)b * S_LEN + h * 256 + (n >> 4);
        int ocol = (n & 15) * 64 + ee;
        att[orow * D_MODEL + ocol] = f2bf(acc[m][nf][j] * z);
      }
    }
}

extern "C" void kernel_launch(void* const* d_in, const int* in_sizes, int n_in,
                              void* d_out, int out_size, void* d_ws, size_t ws_size,
                              hipStream_t stream) {
  (void)in_sizes; (void)n_in; (void)out_size; (void)ws_size;
  const float* q     = (const float*)d_in[0];
  const float* k     = (const float*)d_in[1];
  const float* v     = (const float*)d_in[2];
  const float* mask  = (const float*)d_in[3];
  const float* wq    = (const float*)d_in[4];
  const float* wk    = (const float*)d_in[5];
  const float* wv    = (const float*)d_in[6];
  const float* gamma = (const float*)d_in[7];
  const float* beta  = (const float*)d_in[8];
  const float* dw    = (const float*)d_in[9];
  const float* db    = (const float*)d_in[10];
  float* out = (float*)d_out;

  char* ws = (char*)d_ws;
  unsigned short* Xb  = (unsigned short*)(ws);               // 33.5 MB (also att; part/kspart alias here mid-pipeline)
  unsigned short* Qp  = (unsigned short*)(ws + 33554432);
  unsigned short* Kp  = (unsigned short*)(ws + 67108864);
  unsigned short* Vp  = (unsigned short*)(ws + 100663296);
  unsigned short* WqT = (unsigned short*)(ws + 134217728);
  unsigned short* WkT = WqT + 1048576;
  unsigned short* WvT = WkT + 1048576;
  unsigned short* WdT = WvT + 1048576;
  float* part   = (float*)(ws);             // aliases Xb (dead between v-GEMM and att)
  float* kspart = (float*)(ws + 8388608);   // still inside Xb region
  unsigned short* KVT = (unsigned short*)(ws + 142606336);
  float* ksum = (float*)(ws + 143130624);

  dim3 b256(256);
  int n4 = ROWS * D_MODEL / 4;
  dim3 cvtg(n4 / 256);
  dim3 wtg(32, 32);
  dim3 gemmg(8, 128);
  dim3 lng(ROWS);

  wtrans_k<<<wtg, b256, 0, stream>>>(wq, WqT);
  wtrans_k<<<wtg, b256, 0, stream>>>(wk, WkT);
  wtrans_k<<<wtg, b256, 0, stream>>>(wv, WvT);
  wtrans_k<<<wtg, b256, 0, stream>>>(dw, WdT);

  cvt_f32_bf16_k<<<cvtg, b256, 0, stream>>>(q, Xb, n4);
  gemm_bt_k<<<gemmg, b256, 0, stream>>>(Xb, WqT, out, nullptr, ROWS, D_MODEL, D_MODEL);
  ln_act_k<<<lng, b256, 0, stream>>>(out, gamma, beta, nullptr, Qp, 0);

  cvt_f32_bf16_k<<<cvtg, b256, 0, stream>>>(k, Xb, n4);
  gemm_bt_k<<<gemmg, b256, 0, stream>>>(Xb, WkT, out, nullptr, ROWS, D_MODEL, D_MODEL);
  ln_act_k<<<lng, b256, 0, stream>>>(out, gamma, beta, mask, Kp, 1);

  cvt_f32_bf16_k<<<cvtg, b256, 0, stream>>>(v, Xb, n4);
  gemm_bt_k<<<gemmg, b256, 0, stream>>>(Xb, WvT, out, nullptr, ROWS, D_MODEL, D_MODEL);
  ln_act_k<<<lng, b256, 0, stream>>>(out, gamma, beta, mask, Vp, 2);

  kv_part_k<<<dim3(8, 64), b256, 0, stream>>>(Kp, Vp, part, kspart);
  kv_reduce_k<<<dim3(64), b256, 0, stream>>>(part, kspart, KVT, ksum);
  att_k<<<dim3(32, 64), b256, 0, stream>>>(Qp, KVT, ksum, Xb);

  gemm_bt_k<<<gemmg, b256, 0, stream>>>(Xb, WdT, out, db, ROWS, D_MODEL, D_MODEL);
  ln_final_k<<<lng, b256, 0, stream>>>(out, gamma, beta);
}

// Round 3
// 431.377 us; speedup vs baseline: 1.1540x; 1.1540x over previous
//
#include <hip/hip_runtime.h>
#include <hip/hip_bf16.h>
#include <stdint.h>

#define D_MODEL 1024
#define S_LEN   4096
#define BATCH   4
#define HEADS   16
#define DEPTH   64
#define ROWS    (BATCH*S_LEN)   // 16384
#define EPS_K_F 1e-6f
#define EPS_LN_F 1e-6f

typedef __attribute__((ext_vector_type(8))) short short8;
typedef __attribute__((ext_vector_type(4))) float f32x4;

__device__ __forceinline__ unsigned short f2bf(float f) {
  union { float f; unsigned u; } x; x.f = f;
  unsigned r = x.u + 0x7FFF + ((x.u >> 16) & 1);
  return (unsigned short)(r >> 16);
}
__device__ __forceinline__ float bf2f(unsigned short b) {
  union { unsigned u; float f; } x; x.u = ((unsigned)b) << 16;
  return x.f;
}
__device__ __forceinline__ void gload16(const void* g, void* l) {
  __builtin_amdgcn_global_load_lds(
      (const __attribute__((address_space(1))) void*)g,
      (__attribute__((address_space(3))) void*)l, 16, 0, 0);
}

// ---------------- f32 -> bf16 convert ----------------
__global__ __launch_bounds__(256) void cvt_f32_bf16_k(
    const float* __restrict__ in, unsigned short* __restrict__ out, int n4) {
  int i = blockIdx.x * 256 + threadIdx.x;
  if (i < n4) {
    float4 v = ((const float4*)in)[i];
    ushort4 o;
    o.x = f2bf(v.x); o.y = f2bf(v.y); o.z = f2bf(v.z); o.w = f2bf(v.w);
    ((ushort4*)out)[i] = o;
  }
}

// ---------------- weight transpose + convert: W[K,N] f32 -> Wt[N,K] bf16 ----
__global__ __launch_bounds__(256) void wtrans_k(
    const float* __restrict__ W, unsigned short* __restrict__ Wt) {
  __shared__ float tile[32][33];
  int n0 = blockIdx.x * 32, k0 = blockIdx.y * 32;
  int tx = threadIdx.x & 31, ty = threadIdx.x >> 5;
  #pragma unroll
  for (int i = 0; i < 32; i += 8)
    tile[ty + i][tx] = W[(size_t)(k0 + ty + i) * D_MODEL + n0 + tx];
  __syncthreads();
  #pragma unroll
  for (int i = 0; i < 32; i += 8)
    Wt[(size_t)(n0 + ty + i) * D_MODEL + k0 + tx] = f2bf(tile[tx][ty + i]);
}

// ---------------- bf16 GEMM: A[M,K] @ Bt[N,K]^T -> C[M,N] f32 (+bias) -------
// grid: 1D, (M/128)*(N/128) blocks; XCD-swizzled so all 8 col-tiles of a
// row-panel land on the same XCD (requires N == 1024 -> 8 col tiles).
__global__ __launch_bounds__(256) void gemm_bt_k(
    const unsigned short* __restrict__ A,
    const unsigned short* __restrict__ Bt,
    float* __restrict__ C,
    const float* __restrict__ bias,
    int M, int N, int K) {
  __shared__ unsigned short Al[128 * 64];
  __shared__ unsigned short Bl[128 * 64];
  int t = threadIdx.x;
  int lane = t & 63, wid = t >> 6;
  int wr = wid >> 1, wc = wid & 1;
  int l15 = lane & 15, lhi = lane >> 4;
  int p = blockIdx.x;
  int cb = (p >> 3) & 7;                 // col tile 0..7
  int rb = (p & 7) | ((p >> 6) << 3);    // row tile 0..M/128-1
  size_t m0 = (size_t)rb * 128, n0 = (size_t)cb * 128;
  f32x4 acc[4][4] = {};

  for (int k0 = 0; k0 < K; k0 += 64) {
    #pragma unroll
    for (int i = 0; i < 4; ++i) {
      int cid = i * 256 + t;
      int r = cid >> 3, c8 = cid & 7;
      gload16(A  + (m0 + r) * (size_t)K + k0 + c8 * 8, &Al[cid * 8]);
      gload16(Bt + (n0 + r) * (size_t)K + k0 + c8 * 8, &Bl[cid * 8]);
    }
    asm volatile("s_waitcnt vmcnt(0)" ::: "memory");
    __syncthreads();
    #pragma unroll
    for (int kk = 0; kk < 2; ++kk) {
      short8 af[4], bfr[4];
      #pragma unroll
      for (int m = 0; m < 4; ++m)
        af[m] = *(const short8*)&Al[(wr * 64 + m * 16 + l15) * 64 + kk * 32 + lhi * 8];
      #pragma unroll
      for (int n = 0; n < 4; ++n)
        bfr[n] = *(const short8*)&Bl[(wc * 64 + n * 16 + l15) * 64 + kk * 32 + lhi * 8];
      #pragma unroll
      for (int m = 0; m < 4; ++m)
        #pragma unroll
        for (int n = 0; n < 4; ++n)
          acc[m][n] = __builtin_amdgcn_mfma_f32_16x16x32_bf16(af[m], bfr[n], acc[m][n], 0, 0, 0);
    }
    __syncthreads();
  }
  float bv[4];
  #pragma unroll
  for (int n = 0; n < 4; ++n) {
    int col = (int)n0 + wc * 64 + n * 16 + l15;
    bv[n] = bias ? bias[col] : 0.f;
  }
  #pragma unroll
  for (int m = 0; m < 4; ++m)
    #pragma unroll
    for (int j = 0; j < 4; ++j) {
      size_t row = m0 + wr * 64 + m * 16 + lhi * 4 + j;
      #pragma unroll
      for (int n = 0; n < 4; ++n) {
        int col = (int)n0 + wc * 64 + n * 16 + l15;
        C[row * N + col] = acc[m][n][j] + bv[n];
      }
    }
}

// ---------------- LN + activation -> bf16 -----------------------------------
// mode 0: relu(ln)+eps ; mode 1: (relu(ln)+eps)*mask ; mode 2: ln*mask
__global__ __launch_bounds__(256) void ln_act_k(
    const float* __restrict__ Y, const float* __restrict__ gamma,
    const float* __restrict__ beta, const float* __restrict__ mask,
    unsigned short* __restrict__ out, int mode) {
  int row = blockIdx.x;
  int t = threadIdx.x;
  const float* y = Y + (size_t)row * D_MODEL;
  float4 v = ((const float4*)y)[t];
  float av[4] = {v.x, v.y, v.z, v.w};
  float s = av[0] + av[1] + av[2] + av[3];
  float s2 = av[0]*av[0] + av[1]*av[1] + av[2]*av[2] + av[3]*av[3];
  #pragma unroll
  for (int o = 32; o > 0; o >>= 1) { s += __shfl_xor(s, o); s2 += __shfl_xor(s2, o); }
  __shared__ float red[8];
  int wid = t >> 6, lane = t & 63;
  if (lane == 0) { red[wid] = s; red[4 + wid] = s2; }
  __syncthreads();
  s  = red[0] + red[1] + red[2] + red[3];
  s2 = red[4] + red[5] + red[6] + red[7];
  float mean = s * (1.f / D_MODEL);
  float var = s2 * (1.f / D_MODEL) - mean * mean;
  float rstd = rsqrtf(var + EPS_LN_F);
  float mk = (mode > 0) ? mask[row] : 1.f;
  float4 gv = ((const float4*)gamma)[t];
  float4 bv = ((const float4*)beta)[t];
  float g4[4] = {gv.x, gv.y, gv.z, gv.w};
  float b4[4] = {bv.x, bv.y, bv.z, bv.w};
  unsigned short ov[4];
  #pragma unroll
  for (int j = 0; j < 4; ++j) {
    float ln = (av[j] - mean) * rstd * g4[j] + b4[j];
    if (mode == 0)      ln = fmaxf(ln, 0.f) + EPS_K_F;
    else if (mode == 1) ln = (fmaxf(ln, 0.f) + EPS_K_F) * mk;
    else                ln = ln * mk;
    ov[j] = f2bf(ln);
  }
  ushort4 o; o.x = ov[0]; o.y = ov[1]; o.z = ov[2]; o.w = ov[3];
  ((ushort4*)(out + (size_t)row * D_MODEL))[t] = o;
}

// ---------------- final LayerNorm (in-place, f32) ---------------------------
__global__ __launch_bounds__(256) void ln_final_k(
    float* __restrict__ Y, const float* __restrict__ gamma,
    const float* __restrict__ beta) {
  int row = blockIdx.x;
  int t = threadIdx.x;
  float* y = Y + (size_t)row * D_MODEL;
  float4 v = ((const float4*)y)[t];
  float av[4] = {v.x, v.y, v.z, v.w};
  float s = av[0] + av[1] + av[2] + av[3];
  float s2 = av[0]*av[0] + av[1]*av[1] + av[2]*av[2] + av[3]*av[3];
  #pragma unroll
  for (int o = 32; o > 0; o >>= 1) { s += __shfl_xor(s, o); s2 += __shfl_xor(s2, o); }
  __shared__ float red[8];
  int wid = t >> 6, lane = t & 63;
  if (lane == 0) { red[wid] = s; red[4 + wid] = s2; }
  __syncthreads();
  s  = red[0] + red[1] + red[2] + red[3];
  s2 = red[4] + red[5] + red[6] + red[7];
  float mean = s * (1.f / D_MODEL);
  float var = s2 * (1.f / D_MODEL) - mean * mean;
  float rstd = rsqrtf(var + EPS_LN_F);
  float4 gv = ((const float4*)gamma)[t];
  float4 bv = ((const float4*)beta)[t];
  float4 w;
  w.x = (av[0] - mean) * rstd * gv.x + bv.x;
  w.y = (av[1] - mean) * rstd * gv.y + bv.y;
  w.z = (av[2] - mean) * rstd * gv.z + bv.z;
  w.w = (av[3] - mean) * rstd * gv.w + bv.w;
  __syncthreads();
  ((float4*)y)[t] = w;
}

// ---------------- KV via MFMA with swizzled-LDS transpose -------------------
// Per (b,h,chunk): KV_part[d,e] = sum over 512 n of K'[n,d]*V'[n,e].
// LDS tile layout (per tensor, 64n x 64d): element (n, d) stored at
//   el = n*64 + (((d>>4) ^ ((n>>3)&3)) << 4) + (d & 15)
// The XOR makes transposed per-lane u16 gathers bank-conflict-free and
// b128 staging writes hit the 8-cycle minimum.
__global__ __launch_bounds__(256) void kv_mfma_k(
    const unsigned short* __restrict__ Kp, const unsigned short* __restrict__ Vp,
    float* __restrict__ part, float* __restrict__ kspart) {
  __shared__ unsigned short Kl[4096];
  __shared__ unsigned short Vl[4096];
  int bh = blockIdx.y, chunk = blockIdx.x;   // chunk 0..7, 512 n each
  int b_ = bh >> 4, h = bh & 15;
  int t = threadIdx.x, lane = t & 63, w = t >> 6;
  int l15 = lane & 15, g = lane >> 4;        // g in 0..3

  // staging: thread t owns tile-row n = t>>2, d-chunk d16 = t&3 (16 bf16)
  int sn = t >> 2, sd16 = t & 3;
  int sc = sd16 ^ ((sn >> 3) & 3);
  size_t goff = (size_t)sn * D_MODEL + h * DEPTH + sd16 * 16;
  int ldst = sn * 64 + sc * 16;

  short8 ones;
  #pragma unroll
  for (int i = 0; i < 8; ++i) ones[i] = (short)0x3F80;

  f32x4 acc[4] = {};
  f32x4 ks = {};

  int baseA = ((w ^ g) << 4) + l15;     // A-frag (K): d = 16w + l15
  int baseB0 = ((0 ^ g) << 4) + l15;    // B-frags (V): e = 16nf + l15
  int baseB1 = ((1 ^ g) << 4) + l15;
  int baseB2 = ((2 ^ g) << 4) + l15;
  int baseB3 = ((3 ^ g) << 4) + l15;

  size_t rowbase = ((size_t)b_ * S_LEN + (size_t)chunk * 512) * D_MODEL;
  for (int tile = 0; tile < 8; ++tile) {
    const unsigned short* kg = Kp + rowbase + (size_t)tile * 64 * D_MODEL + goff;
    const unsigned short* vg = Vp + rowbase + (size_t)tile * 64 * D_MODEL + goff;
    uint4 ra = *(const uint4*)kg;
    uint4 rb = *(const uint4*)(kg + 8);
    uint4 rc = *(const uint4*)vg;
    uint4 rd = *(const uint4*)(vg + 8);
    __syncthreads();                    // prev tile's reads complete
    *(uint4*)&Kl[ldst]     = ra;
    *(uint4*)&Kl[ldst + 8] = rb;
    *(uint4*)&Vl[ldst]     = rc;
    *(uint4*)&Vl[ldst + 8] = rd;
    __syncthreads();
    #pragma unroll
    for (int kk = 0; kk < 2; ++kk) {
      int nb = (kk * 32 + g * 8) * 64;
      short8 af, bf0, bf1, bf2, bf3;
      #pragma unroll
      for (int i = 0; i < 8; ++i) {
        int rowoff = nb + i * 64;
        af[i]  = (short)Kl[rowoff + baseA];
        bf0[i] = (short)Vl[rowoff + baseB0];
        bf1[i] = (short)Vl[rowoff + baseB1];
        bf2[i] = (short)Vl[rowoff + baseB2];
        bf3[i] = (short)Vl[rowoff + baseB3];
      }
      acc[0] = __builtin_amdgcn_mfma_f32_16x16x32_bf16(af, bf0, acc[0], 0, 0, 0);
      acc[1] = __builtin_amdgcn_mfma_f32_16x16x32_bf16(af, bf1, acc[1], 0, 0, 0);
      acc[2] = __builtin_amdgcn_mfma_f32_16x16x32_bf16(af, bf2, acc[2], 0, 0, 0);
      acc[3] = __builtin_amdgcn_mfma_f32_16x16x32_bf16(af, bf3, acc[3], 0, 0, 0);
      ks     = __builtin_amdgcn_mfma_f32_16x16x32_bf16(af, ones, ks, 0, 0, 0);
    }
  }
  // acc[nf][r]: d = 16w + 4g + r, e = 16nf + l15  (C-layout: col=l15, row=4g+r)
  float* pp = part + ((size_t)bh * 8 + chunk) * 4096;
  #pragma unroll
  for (int nf = 0; nf < 4; ++nf)
    #pragma unroll
    for (int r = 0; r < 4; ++r)
      pp[(16 * w + 4 * g + r) * 64 + 16 * nf + l15] = acc[nf][r];
  if (l15 == 0) {
    #pragma unroll
    for (int r = 0; r < 4; ++r)
      kspart[((size_t)bh * 8 + chunk) * 64 + 16 * w + 4 * g + r] = ks[r];
  }
}

// ---------------- KV reduce -> KV^T bf16 ([e][d]) + ksum f32 ----------------
__global__ __launch_bounds__(256) void kv_reduce_k(
    const float* __restrict__ part, const float* __restrict__ kspart,
    unsigned short* __restrict__ KVT, float* __restrict__ ksum) {
  int bh = blockIdx.x, t = threadIdx.x;
  for (int idx = t; idx < 4096; idx += 256) {
    int d = idx >> 6, e = idx & 63;
    float s = 0.f;
    #pragma unroll
    for (int c = 0; c < 8; ++c)
      s += part[((size_t)bh * 8 + c) * 4096 + d * 64 + e];
    KVT[(size_t)bh * 4096 + e * 64 + d] = f2bf(s);
  }
  if (t < 64) {
    float s = 0.f;
    #pragma unroll
    for (int c = 0; c < 8; ++c) s += kspart[((size_t)bh * 8 + c) * 64 + t];
    ksum[bh * 64 + t] = s;
  }
}

// ---------------- att = (q' @ KV) * z, written in the reference's reshape ---
__global__ __launch_bounds__(256) void att_k(
    const unsigned short* __restrict__ Qp, const unsigned short* __restrict__ KVT,
    const float* __restrict__ ksum, unsigned short* __restrict__ att) {
  __shared__ unsigned short Ql[128 * 64];
  __shared__ unsigned short Kl[64 * 64];
  __shared__ float ksl[64];
  __shared__ float zl[128];
  int bh = blockIdx.y;
  int b = bh >> 4, h = bh & 15;
  int r0 = blockIdx.x * 128;
  int t = threadIdx.x, lane = t & 63, wid = t >> 6;
  int l15 = lane & 15, lhi = lane >> 4;
  #pragma unroll
  for (int i = 0; i < 4; ++i) {
    int cid = i * 256 + t;
    int r = cid >> 3, c8 = cid & 7;
    gload16(Qp + ((size_t)(b * S_LEN + r0 + r)) * D_MODEL + h * DEPTH + c8 * 8,
            &Ql[cid * 8]);
  }
  #pragma unroll
  for (int i = 0; i < 2; ++i) {
    int cid = i * 256 + t;
    gload16(KVT + (size_t)bh * 4096 + cid * 8, &Kl[cid * 8]);
  }
  if (t < 64) ksl[t] = ksum[bh * 64 + t];
  asm volatile("s_waitcnt vmcnt(0)" ::: "memory");
  __syncthreads();
  {
    int r = t >> 1, half = t & 1;
    float s = 0.f;
    #pragma unroll
    for (int j = 0; j < 32; ++j)
      s += bf2f(Ql[r * 64 + half * 32 + j]) * ksl[half * 32 + j];
    s += __shfl_xor(s, 1);
    if (half == 0) zl[r] = 1.f / (s + EPS_K_F);
  }
  __syncthreads();
  f32x4 acc[2][4] = {};
  #pragma unroll
  for (int kk = 0; kk < 2; ++kk) {
    short8 af[2], bfr[4];
    #pragma unroll
    for (int m = 0; m < 2; ++m)
      af[m] = *(const short8*)&Ql[(wid * 32 + m * 16 + l15) * 64 + kk * 32 + lhi * 8];
    #pragma unroll
    for (int n = 0; n < 4; ++n)
      bfr[n] = *(const short8*)&Kl[(n * 16 + l15) * 64 + kk * 32 + lhi * 8];
    #pragma unroll
    for (int m = 0; m < 2; ++m)
      #pragma unroll
      for (int n = 0; n < 4; ++n)
        acc[m][n] = __builtin_amdgcn_mfma_f32_16x16x32_bf16(af[m], bfr[n], acc[m][n], 0, 0, 0);
  }
  // reference reshape: att_flat[b, h*256 + n/16, (n%16)*64 + e]
  #pragma unroll
  for (int m = 0; m < 2; ++m)
    #pragma unroll
    for (int j = 0; j < 4; ++j) {
      int rl = wid * 32 + m * 16 + lhi * 4 + j;
      int n = r0 + rl;
      float z = zl[rl];
      #pragma unroll
      for (int nf = 0; nf < 4; ++nf) {
        int ee = nf * 16 + l15;
        size_t orow = (size_t)b * S_LEN + h * 256 + (n >> 4);
        int ocol = (n & 15) * 64 + ee;
        att[orow * D_MODEL + ocol] = f2bf(acc[m][nf][j] * z);
      }
    }
}

extern "C" void kernel_launch(void* const* d_in, const int* in_sizes, int n_in,
                              void* d_out, int out_size, void* d_ws, size_t ws_size,
                              hipStream_t stream) {
  (void)in_sizes; (void)n_in; (void)out_size; (void)ws_size;
  const float* q     = (const float*)d_in[0];
  const float* k     = (const float*)d_in[1];
  const float* v     = (const float*)d_in[2];
  const float* mask  = (const float*)d_in[3];
  const float* wq    = (const float*)d_in[4];
  const float* wk    = (const float*)d_in[5];
  const float* wv    = (const float*)d_in[6];
  const float* gamma = (const float*)d_in[7];
  const float* beta  = (const float*)d_in[8];
  const float* dw    = (const float*)d_in[9];
  const float* db    = (const float*)d_in[10];
  float* out = (float*)d_out;

  char* ws = (char*)d_ws;
  unsigned short* Xb  = (unsigned short*)(ws);               // 33.5 MB (also att; part/kspart alias here mid-pipeline)
  unsigned short* Qp  = (unsigned short*)(ws + 33554432);
  unsigned short* Kp  = (unsigned short*)(ws + 67108864);
  unsigned short* Vp  = (unsigned short*)(ws + 100663296);
  unsigned short* WqT = (unsigned short*)(ws + 134217728);
  unsigned short* WkT = WqT + 1048576;
  unsigned short* WvT = WkT + 1048576;
  unsigned short* WdT = WvT + 1048576;
  float* part   = (float*)(ws);             // aliases Xb (dead between v-GEMM and att)
  float* kspart = (float*)(ws + 8388608);   // still inside Xb region
  unsigned short* KVT = (unsigned short*)(ws + 142606336);
  float* ksum = (float*)(ws + 143130624);

  dim3 b256(256);
  int n4 = ROWS * D_MODEL / 4;
  dim3 cvtg(n4 / 256);
  dim3 wtg(32, 32);
  dim3 gemmg(1024);           // (M/128)*(N/128), XCD-swizzled in-kernel
  dim3 lng(ROWS);

  wtrans_k<<<wtg, b256, 0, stream>>>(wq, WqT);
  wtrans_k<<<wtg, b256, 0, stream>>>(wk, WkT);
  wtrans_k<<<wtg, b256, 0, stream>>>(wv, WvT);
  wtrans_k<<<wtg, b256, 0, stream>>>(dw, WdT);

  cvt_f32_bf16_k<<<cvtg, b256, 0, stream>>>(q, Xb, n4);
  gemm_bt_k<<<gemmg, b256, 0, stream>>>(Xb, WqT, out, nullptr, ROWS, D_MODEL, D_MODEL);
  ln_act_k<<<lng, b256, 0, stream>>>(out, gamma, beta, nullptr, Qp, 0);

  cvt_f32_bf16_k<<<cvtg, b256, 0, stream>>>(k, Xb, n4);
  gemm_bt_k<<<gemmg, b256, 0, stream>>>(Xb, WkT, out, nullptr, ROWS, D_MODEL, D_MODEL);
  ln_act_k<<<lng, b256, 0, stream>>>(out, gamma, beta, mask, Kp, 1);

  cvt_f32_bf16_k<<<cvtg, b256, 0, stream>>>(v, Xb, n4);
  gemm_bt_k<<<gemmg, b256, 0, stream>>>(Xb, WvT, out, nullptr, ROWS, D_MODEL, D_MODEL);
  ln_act_k<<<lng, b256, 0, stream>>>(out, gamma, beta, mask, Vp, 2);

  kv_mfma_k<<<dim3(8, 64), b256, 0, stream>>>(Kp, Vp, part, kspart);
  kv_reduce_k<<<dim3(64), b256, 0, stream>>>(part, kspart, KVT, ksum);
  att_k<<<dim3(32, 64), b256, 0, stream>>>(Qp, KVT, ksum, Xb);

  gemm_bt_k<<<gemmg, b256, 0, stream>>>(Xb, WdT, out, db, ROWS, D_MODEL, D_MODEL);
  ln_final_k<<<lng, b256, 0, stream>>>(out, gamma, beta);
}

// Round 4
// 425.560 us; speedup vs baseline: 1.1698x; 1.0137x over previous
//
#include <hip/hip_runtime.h>
#include <hip/hip_bf16.h>
#include <stdint.h>

#define D_MODEL 1024
#define S_LEN   4096
#define BATCH   4
#define HEADS   16
#define DEPTH   64
#define ROWS    (BATCH*S_LEN)   // 16384
#define EPS_K_F 1e-6f
#define EPS_LN_F 1e-6f

typedef __attribute__((ext_vector_type(8))) short short8;
typedef __attribute__((ext_vector_type(4))) float f32x4;

__device__ __forceinline__ unsigned short f2bf(float f) {
  union { float f; unsigned u; } x; x.f = f;
  unsigned r = x.u + 0x7FFF + ((x.u >> 16) & 1);
  return (unsigned short)(r >> 16);
}
__device__ __forceinline__ float bf2f(unsigned short b) {
  union { unsigned u; float f; } x; x.u = ((unsigned)b) << 16;
  return x.f;
}
__device__ __forceinline__ void gload16(const void* g, void* l) {
  __builtin_amdgcn_global_load_lds(
      (const __attribute__((address_space(1))) void*)g,
      (__attribute__((address_space(3))) void*)l, 16, 0, 0);
}

// ---------------- f32 -> bf16 convert ----------------
__global__ __launch_bounds__(256) void cvt_f32_bf16_k(
    const float* __restrict__ in, unsigned short* __restrict__ out, int n4) {
  int i = blockIdx.x * 256 + threadIdx.x;
  if (i < n4) {
    float4 v = ((const float4*)in)[i];
    ushort4 o;
    o.x = f2bf(v.x); o.y = f2bf(v.y); o.z = f2bf(v.z); o.w = f2bf(v.w);
    ((ushort4*)out)[i] = o;
  }
}

// ---------------- weight transpose + convert: W[K,N] f32 -> Wt[N,K] bf16 ----
__global__ __launch_bounds__(256) void wtrans_k(
    const float* __restrict__ W, unsigned short* __restrict__ Wt) {
  __shared__ float tile[32][33];
  int n0 = blockIdx.x * 32, k0 = blockIdx.y * 32;
  int tx = threadIdx.x & 31, ty = threadIdx.x >> 5;
  #pragma unroll
  for (int i = 0; i < 32; i += 8)
    tile[ty + i][tx] = W[(size_t)(k0 + ty + i) * D_MODEL + n0 + tx];
  __syncthreads();
  #pragma unroll
  for (int i = 0; i < 32; i += 8)
    Wt[(size_t)(n0 + ty + i) * D_MODEL + k0 + tx] = f2bf(tile[tx][ty + i]);
}

// ---------------- bf16 GEMM: A[M,K] @ Bt[N,K]^T -> Cb[M,N] bf16 (+bias) -----
// Double-buffered LDS (min-2-phase): stage tile t+1 before computing tile t.
// Epilogue: adds bias, writes bf16 C, and per-(row, 64-col segment) partial
// sum/sumsq for downstream LayerNorm (deterministic shuffle reduction).
// grid: 1D, (M/128)*(N/128) blocks; XCD-swizzled (requires N == 1024).
__global__ __launch_bounds__(256) void gemm_bt_k(
    const unsigned short* __restrict__ A,
    const unsigned short* __restrict__ Bt,
    unsigned short* __restrict__ Cb,
    float* __restrict__ psum, float* __restrict__ psq,
    const float* __restrict__ bias,
    int M, int N, int K) {
  __shared__ unsigned short Al[2][128 * 64];
  __shared__ unsigned short Bl[2][128 * 64];
  int t = threadIdx.x;
  int lane = t & 63, wid = t >> 6;
  int wr = wid >> 1, wc = wid & 1;
  int l15 = lane & 15, lhi = lane >> 4;
  int p = blockIdx.x;
  int cb = (p >> 3) & 7;                 // col tile 0..7
  int rb = (p & 7) | ((p >> 6) << 3);    // row tile 0..M/128-1
  size_t m0 = (size_t)rb * 128, n0 = (size_t)cb * 128;
  f32x4 acc[4][4] = {};

  int cid = t;                            // staging ids t, t+256, t+512, t+768
  const int KT = K >> 6;                  // 16 K-tiles of 64

  // prologue: stage tile 0 into buf 0
  #pragma unroll
  for (int i = 0; i < 4; ++i) {
    int c = i * 256 + t, r = c >> 3, c8 = c & 7;
    gload16(A  + (m0 + r) * (size_t)K + c8 * 8, &Al[0][c * 8]);
    gload16(Bt + (n0 + r) * (size_t)K + c8 * 8, &Bl[0][c * 8]);
  }
  __syncthreads();

  int pb = 0;
  for (int kt = 0; kt < KT; ++kt) {
    if (kt + 1 < KT) {
      int k0 = (kt + 1) << 6;
      #pragma unroll
      for (int i = 0; i < 4; ++i) {
        int c = i * 256 + t, r = c >> 3, c8 = c & 7;
        gload16(A  + (m0 + r) * (size_t)K + k0 + c8 * 8, &Al[pb ^ 1][c * 8]);
        gload16(Bt + (n0 + r) * (size_t)K + k0 + c8 * 8, &Bl[pb ^ 1][c * 8]);
      }
    }
    #pragma unroll
    for (int kk = 0; kk < 2; ++kk) {
      short8 af[4], bfr[4];
      #pragma unroll
      for (int m = 0; m < 4; ++m)
        af[m] = *(const short8*)&Al[pb][(wr * 64 + m * 16 + l15) * 64 + kk * 32 + lhi * 8];
      #pragma unroll
      for (int n = 0; n < 4; ++n)
        bfr[n] = *(const short8*)&Bl[pb][(wc * 64 + n * 16 + l15) * 64 + kk * 32 + lhi * 8];
      #pragma unroll
      for (int m = 0; m < 4; ++m)
        #pragma unroll
        for (int n = 0; n < 4; ++n)
          acc[m][n] = __builtin_amdgcn_mfma_f32_16x16x32_bf16(af[m], bfr[n], acc[m][n], 0, 0, 0);
    }
    __syncthreads();   // drains vmcnt(0)+lgkmcnt(0) then barrier
    pb ^= 1;
  }
  (void)cid;

  // bias into acc first (stats must include bias, like reference)
  if (bias) {
    float bv[4];
    #pragma unroll
    for (int n = 0; n < 4; ++n)
      bv[n] = bias[(int)n0 + wc * 64 + n * 16 + l15];
    #pragma unroll
    for (int m = 0; m < 4; ++m)
      #pragma unroll
      for (int n = 0; n < 4; ++n)
        #pragma unroll
        for (int j = 0; j < 4; ++j)
          acc[m][n][j] += bv[n];
  }

  // per-row partial sum / sumsq over this block's 128 cols (per 64-col wave)
  int seg = (int)(n0 >> 6) + wc;          // 0..15
  #pragma unroll
  for (int m = 0; m < 4; ++m) {
    float s[4], s2[4];
    #pragma unroll
    for (int j = 0; j < 4; ++j) {
      float a = 0.f, b = 0.f;
      #pragma unroll
      for (int n = 0; n < 4; ++n) {
        float x = acc[m][n][j];
        a += x; b += x * x;
      }
      s[j] = a; s2[j] = b;
    }
    #pragma unroll
    for (int off = 1; off < 16; off <<= 1) {
      #pragma unroll
      for (int j = 0; j < 4; ++j) {
        s[j]  += __shfl_xor(s[j],  off);
        s2[j] += __shfl_xor(s2[j], off);
      }
    }
    if (l15 == 0) {
      #pragma unroll
      for (int j = 0; j < 4; ++j) {
        int rg = (int)m0 + wr * 64 + m * 16 + lhi * 4 + j;
        psum[rg * 16 + seg] = s[j];
        psq [rg * 16 + seg] = s2[j];
      }
    }
  }

  // bf16 C write
  #pragma unroll
  for (int m = 0; m < 4; ++m)
    #pragma unroll
    for (int j = 0; j < 4; ++j) {
      size_t row = m0 + wr * 64 + m * 16 + lhi * 4 + j;
      #pragma unroll
      for (int n = 0; n < 4; ++n) {
        int col = (int)n0 + wc * 64 + n * 16 + l15;
        Cb[row * N + col] = f2bf(acc[m][n][j]);
      }
    }
}

// ---------------- LN + activation from bf16 C + partials -> bf16 ------------
// mode 0: relu(ln)+eps ; mode 1: (relu(ln)+eps)*mask ; mode 2: ln*mask
__global__ __launch_bounds__(256) void ln_act_k(
    const unsigned short* __restrict__ Cb,
    const float* __restrict__ psum, const float* __restrict__ psq,
    const float* __restrict__ gamma, const float* __restrict__ beta,
    const float* __restrict__ mask,
    unsigned short* __restrict__ out, int mode) {
  int row = blockIdx.x;
  int t = threadIdx.x;
  float s = 0.f, s2 = 0.f;
  #pragma unroll
  for (int i = 0; i < 16; ++i) { s += psum[row * 16 + i]; s2 += psq[row * 16 + i]; }
  float mean = s * (1.f / D_MODEL);
  float var = s2 * (1.f / D_MODEL) - mean * mean;
  float rstd = rsqrtf(var + EPS_LN_F);
  float mk = (mode > 0) ? mask[row] : 1.f;
  ushort4 cv = ((const ushort4*)(Cb + (size_t)row * D_MODEL))[t];
  float4 gv = ((const float4*)gamma)[t];
  float4 bv = ((const float4*)beta)[t];
  float av[4] = {bf2f(cv.x), bf2f(cv.y), bf2f(cv.z), bf2f(cv.w)};
  float g4[4] = {gv.x, gv.y, gv.z, gv.w};
  float b4[4] = {bv.x, bv.y, bv.z, bv.w};
  unsigned short ov[4];
  #pragma unroll
  for (int j = 0; j < 4; ++j) {
    float ln = (av[j] - mean) * rstd * g4[j] + b4[j];
    if (mode == 0)      ln = fmaxf(ln, 0.f) + EPS_K_F;
    else if (mode == 1) ln = (fmaxf(ln, 0.f) + EPS_K_F) * mk;
    else                ln = ln * mk;
    ov[j] = f2bf(ln);
  }
  ushort4 o; o.x = ov[0]; o.y = ov[1]; o.z = ov[2]; o.w = ov[3];
  ((ushort4*)(out + (size_t)row * D_MODEL))[t] = o;
}

// ---------------- final LayerNorm from bf16 C + partials -> f32 out ---------
__global__ __launch_bounds__(256) void ln_final_k(
    const unsigned short* __restrict__ Cb,
    const float* __restrict__ psum, const float* __restrict__ psq,
    const float* __restrict__ gamma, const float* __restrict__ beta,
    float* __restrict__ out) {
  int row = blockIdx.x;
  int t = threadIdx.x;
  float s = 0.f, s2 = 0.f;
  #pragma unroll
  for (int i = 0; i < 16; ++i) { s += psum[row * 16 + i]; s2 += psq[row * 16 + i]; }
  float mean = s * (1.f / D_MODEL);
  float var = s2 * (1.f / D_MODEL) - mean * mean;
  float rstd = rsqrtf(var + EPS_LN_F);
  ushort4 cv = ((const ushort4*)(Cb + (size_t)row * D_MODEL))[t];
  float4 gv = ((const float4*)gamma)[t];
  float4 bv = ((const float4*)beta)[t];
  float4 w;
  w.x = (bf2f(cv.x) - mean) * rstd * gv.x + bv.x;
  w.y = (bf2f(cv.y) - mean) * rstd * gv.y + bv.y;
  w.z = (bf2f(cv.z) - mean) * rstd * gv.z + bv.z;
  w.w = (bf2f(cv.w) - mean) * rstd * gv.w + bv.w;
  ((float4*)(out + (size_t)row * D_MODEL))[t] = w;
}

// ---------------- KV via MFMA with swizzled-LDS transpose -------------------
__global__ __launch_bounds__(256) void kv_mfma_k(
    const unsigned short* __restrict__ Kp, const unsigned short* __restrict__ Vp,
    float* __restrict__ part, float* __restrict__ kspart) {
  __shared__ unsigned short Kl[4096];
  __shared__ unsigned short Vl[4096];
  int bh = blockIdx.y, chunk = blockIdx.x;   // chunk 0..7, 512 n each
  int b_ = bh >> 4, h = bh & 15;
  int t = threadIdx.x, lane = t & 63, w = t >> 6;
  int l15 = lane & 15, g = lane >> 4;        // g in 0..3

  int sn = t >> 2, sd16 = t & 3;
  int sc = sd16 ^ ((sn >> 3) & 3);
  size_t goff = (size_t)sn * D_MODEL + h * DEPTH + sd16 * 16;
  int ldst = sn * 64 + sc * 16;

  short8 ones;
  #pragma unroll
  for (int i = 0; i < 8; ++i) ones[i] = (short)0x3F80;

  f32x4 acc[4] = {};
  f32x4 ks = {};

  int baseA = ((w ^ g) << 4) + l15;
  int baseB0 = ((0 ^ g) << 4) + l15;
  int baseB1 = ((1 ^ g) << 4) + l15;
  int baseB2 = ((2 ^ g) << 4) + l15;
  int baseB3 = ((3 ^ g) << 4) + l15;

  size_t rowbase = ((size_t)b_ * S_LEN + (size_t)chunk * 512) * D_MODEL;
  for (int tile = 0; tile < 8; ++tile) {
    const unsigned short* kg = Kp + rowbase + (size_t)tile * 64 * D_MODEL + goff;
    const unsigned short* vg = Vp + rowbase + (size_t)tile * 64 * D_MODEL + goff;
    uint4 ra = *(const uint4*)kg;
    uint4 rb = *(const uint4*)(kg + 8);
    uint4 rc = *(const uint4*)vg;
    uint4 rd = *(const uint4*)(vg + 8);
    __syncthreads();
    *(uint4*)&Kl[ldst]     = ra;
    *(uint4*)&Kl[ldst + 8] = rb;
    *(uint4*)&Vl[ldst]     = rc;
    *(uint4*)&Vl[ldst + 8] = rd;
    __syncthreads();
    #pragma unroll
    for (int kk = 0; kk < 2; ++kk) {
      int nb = (kk * 32 + g * 8) * 64;
      short8 af, bf0, bf1, bf2, bf3;
      #pragma unroll
      for (int i = 0; i < 8; ++i) {
        int rowoff = nb + i * 64;
        af[i]  = (short)Kl[rowoff + baseA];
        bf0[i] = (short)Vl[rowoff + baseB0];
        bf1[i] = (short)Vl[rowoff + baseB1];
        bf2[i] = (short)Vl[rowoff + baseB2];
        bf3[i] = (short)Vl[rowoff + baseB3];
      }
      acc[0] = __builtin_amdgcn_mfma_f32_16x16x32_bf16(af, bf0, acc[0], 0, 0, 0);
      acc[1] = __builtin_amdgcn_mfma_f32_16x16x32_bf16(af, bf1, acc[1], 0, 0, 0);
      acc[2] = __builtin_amdgcn_mfma_f32_16x16x32_bf16(af, bf2, acc[2], 0, 0, 0);
      acc[3] = __builtin_amdgcn_mfma_f32_16x16x32_bf16(af, bf3, acc[3], 0, 0, 0);
      ks     = __builtin_amdgcn_mfma_f32_16x16x32_bf16(af, ones, ks, 0, 0, 0);
    }
  }
  float* pp = part + ((size_t)bh * 8 + chunk) * 4096;
  #pragma unroll
  for (int nf = 0; nf < 4; ++nf)
    #pragma unroll
    for (int r = 0; r < 4; ++r)
      pp[(16 * w + 4 * g + r) * 64 + 16 * nf + l15] = acc[nf][r];
  if (l15 == 0) {
    #pragma unroll
    for (int r = 0; r < 4; ++r)
      kspart[((size_t)bh * 8 + chunk) * 64 + 16 * w + 4 * g + r] = ks[r];
  }
}

// ---------------- KV reduce -> KV^T bf16 ([e][d]) + ksum f32 ----------------
__global__ __launch_bounds__(256) void kv_reduce_k(
    const float* __restrict__ part, const float* __restrict__ kspart,
    unsigned short* __restrict__ KVT, float* __restrict__ ksum) {
  int bh = blockIdx.x, t = threadIdx.x;
  for (int idx = t; idx < 4096; idx += 256) {
    int d = idx >> 6, e = idx & 63;
    float s = 0.f;
    #pragma unroll
    for (int c = 0; c < 8; ++c)
      s += part[((size_t)bh * 8 + c) * 4096 + d * 64 + e];
    KVT[(size_t)bh * 4096 + e * 64 + d] = f2bf(s);
  }
  if (t < 64) {
    float s = 0.f;
    #pragma unroll
    for (int c = 0; c < 8; ++c) s += kspart[((size_t)bh * 8 + c) * 64 + t];
    ksum[bh * 64 + t] = s;
  }
}

// ---------------- att = (q' @ KV) * z, written in the reference's reshape ---
__global__ __launch_bounds__(256) void att_k(
    const unsigned short* __restrict__ Qp, const unsigned short* __restrict__ KVT,
    const float* __restrict__ ksum, unsigned short* __restrict__ att) {
  __shared__ unsigned short Ql[128 * 64];
  __shared__ unsigned short Kl[64 * 64];
  __shared__ float ksl[64];
  __shared__ float zl[128];
  int bh = blockIdx.y;
  int b = bh >> 4, h = bh & 15;
  int r0 = blockIdx.x * 128;
  int t = threadIdx.x, lane = t & 63, wid = t >> 6;
  int l15 = lane & 15, lhi = lane >> 4;
  #pragma unroll
  for (int i = 0; i < 4; ++i) {
    int cid = i * 256 + t;
    int r = cid >> 3, c8 = cid & 7;
    gload16(Qp + ((size_t)(b * S_LEN + r0 + r)) * D_MODEL + h * DEPTH + c8 * 8,
            &Ql[cid * 8]);
  }
  #pragma unroll
  for (int i = 0; i < 2; ++i) {
    int cid = i * 256 + t;
    gload16(KVT + (size_t)bh * 4096 + cid * 8, &Kl[cid * 8]);
  }
  if (t < 64) ksl[t] = ksum[bh * 64 + t];
  asm volatile("s_waitcnt vmcnt(0)" ::: "memory");
  __syncthreads();
  {
    int r = t >> 1, half = t & 1;
    float s = 0.f;
    #pragma unroll
    for (int j = 0; j < 32; ++j)
      s += bf2f(Ql[r * 64 + half * 32 + j]) * ksl[half * 32 + j];
    s += __shfl_xor(s, 1);
    if (half == 0) zl[r] = 1.f / (s + EPS_K_F);
  }
  __syncthreads();
  f32x4 acc[2][4] = {};
  #pragma unroll
  for (int kk = 0; kk < 2; ++kk) {
    short8 af[2], bfr[4];
    #pragma unroll
    for (int m = 0; m < 2; ++m)
      af[m] = *(const short8*)&Ql[(wid * 32 + m * 16 + l15) * 64 + kk * 32 + lhi * 8];
    #pragma unroll
    for (int n = 0; n < 4; ++n)
      bfr[n] = *(const short8*)&Kl[(n * 16 + l15) * 64 + kk * 32 + lhi * 8];
    #pragma unroll
    for (int m = 0; m < 2; ++m)
      #pragma unroll
      for (int n = 0; n < 4; ++n)
        acc[m][n] = __builtin_amdgcn_mfma_f32_16x16x32_bf16(af[m], bfr[n], acc[m][n], 0, 0, 0);
  }
  #pragma unroll
  for (int m = 0; m < 2; ++m)
    #pragma unroll
    for (int j = 0; j < 4; ++j) {
      int rl = wid * 32 + m * 16 + lhi * 4 + j;
      int n = r0 + rl;
      float z = zl[rl];
      #pragma unroll
      for (int nf = 0; nf < 4; ++nf) {
        int ee = nf * 16 + l15;
        size_t orow = (size_t)b * S_LEN + h * 256 + (n >> 4);
        int ocol = (n & 15) * 64 + ee;
        att[orow * D_MODEL + ocol] = f2bf(acc[m][nf][j] * z);
      }
    }
}

extern "C" void kernel_launch(void* const* d_in, const int* in_sizes, int n_in,
                              void* d_out, int out_size, void* d_ws, size_t ws_size,
                              hipStream_t stream) {
  (void)in_sizes; (void)n_in; (void)out_size; (void)ws_size;
  const float* q     = (const float*)d_in[0];
  const float* k     = (const float*)d_in[1];
  const float* v     = (const float*)d_in[2];
  const float* mask  = (const float*)d_in[3];
  const float* wq    = (const float*)d_in[4];
  const float* wk    = (const float*)d_in[5];
  const float* wv    = (const float*)d_in[6];
  const float* gamma = (const float*)d_in[7];
  const float* beta  = (const float*)d_in[8];
  const float* dw    = (const float*)d_in[9];
  const float* db    = (const float*)d_in[10];
  float* out = (float*)d_out;

  char* ws = (char*)d_ws;
  unsigned short* Xb  = (unsigned short*)(ws);               // 33.5 MB
  unsigned short* Qp  = (unsigned short*)(ws + 33554432);    // also dense-C after att
  unsigned short* Kp  = (unsigned short*)(ws + 67108864);
  unsigned short* Vp  = (unsigned short*)(ws + 100663296);
  unsigned short* WqT = (unsigned short*)(ws + 134217728);
  unsigned short* WkT = WqT + 1048576;
  unsigned short* WvT = WkT + 1048576;
  unsigned short* WdT = WvT + 1048576;
  float* part   = (float*)(ws);             // aliases Xb (dead mid-pipeline)
  float* kspart = (float*)(ws + 8388608);
  unsigned short* KVT = (unsigned short*)(ws + 142606336);
  float* ksum = (float*)(ws + 143130624);
  float* psum = (float*)(ws + 143654912);   // 16384*16 f32 = 1 MB
  float* psq  = (float*)(ws + 144703488);   // 1 MB
  unsigned short* Cqkv = (unsigned short*)d_out;   // bf16 C scratch (32 MB of 67)
  unsigned short* Cd   = Qp;                       // dense C: Qp dead after att_k

  dim3 b256(256);
  int n4 = ROWS * D_MODEL / 4;
  dim3 cvtg(n4 / 256);
  dim3 wtg(32, 32);
  dim3 gemmg(1024);           // (M/128)*(N/128), XCD-swizzled in-kernel
  dim3 lng(ROWS);

  wtrans_k<<<wtg, b256, 0, stream>>>(wq, WqT);
  wtrans_k<<<wtg, b256, 0, stream>>>(wk, WkT);
  wtrans_k<<<wtg, b256, 0, stream>>>(wv, WvT);
  wtrans_k<<<wtg, b256, 0, stream>>>(dw, WdT);

  cvt_f32_bf16_k<<<cvtg, b256, 0, stream>>>(q, Xb, n4);
  gemm_bt_k<<<gemmg, b256, 0, stream>>>(Xb, WqT, Cqkv, psum, psq, nullptr, ROWS, D_MODEL, D_MODEL);
  ln_act_k<<<lng, b256, 0, stream>>>(Cqkv, psum, psq, gamma, beta, nullptr, Qp, 0);

  cvt_f32_bf16_k<<<cvtg, b256, 0, stream>>>(k, Xb, n4);
  gemm_bt_k<<<gemmg, b256, 0, stream>>>(Xb, WkT, Cqkv, psum, psq, nullptr, ROWS, D_MODEL, D_MODEL);
  ln_act_k<<<lng, b256, 0, stream>>>(Cqkv, psum, psq, gamma, beta, mask, Kp, 1);

  cvt_f32_bf16_k<<<cvtg, b256, 0, stream>>>(v, Xb, n4);
  gemm_bt_k<<<gemmg, b256, 0, stream>>>(Xb, WvT, Cqkv, psum, psq, nullptr, ROWS, D_MODEL, D_MODEL);
  ln_act_k<<<lng, b256, 0, stream>>>(Cqkv, psum, psq, gamma, beta, mask, Vp, 2);

  kv_mfma_k<<<dim3(8, 64), b256, 0, stream>>>(Kp, Vp, part, kspart);
  kv_reduce_k<<<dim3(64), b256, 0, stream>>>(part, kspart, KVT, ksum);
  att_k<<<dim3(32, 64), b256, 0, stream>>>(Qp, KVT, ksum, Xb);

  gemm_bt_k<<<gemmg, b256, 0, stream>>>(Xb, WdT, Cd, psum, psq, db, ROWS, D_MODEL, D_MODEL);
  ln_final_k<<<lng, b256, 0, stream>>>(Cd, psum, psq, gamma, beta, out);
}

// Round 5
// 362.005 us; speedup vs baseline: 1.3752x; 1.1756x over previous
//
#include <hip/hip_runtime.h>
#include <hip/hip_bf16.h>
#include <stdint.h>

#define D_MODEL 1024
#define S_LEN   4096
#define BATCH   4
#define HEADS   16
#define DEPTH   64
#define ROWS    (BATCH*S_LEN)   // 16384
#define EPS_K_F 1e-6f
#define EPS_LN_F 1e-6f

typedef __attribute__((ext_vector_type(8))) short short8;
typedef __attribute__((ext_vector_type(4))) float f32x4;

__device__ __forceinline__ unsigned short f2bf(float f) {
  union { float f; unsigned u; } x; x.f = f;
  unsigned r = x.u + 0x7FFF + ((x.u >> 16) & 1);
  return (unsigned short)(r >> 16);
}
__device__ __forceinline__ float bf2f(unsigned short b) {
  union { unsigned u; float f; } x; x.u = ((unsigned)b) << 16;
  return x.f;
}
__device__ __forceinline__ void gload16(const void* g, void* l) {
  __builtin_amdgcn_global_load_lds(
      (const __attribute__((address_space(1))) void*)g,
      (__attribute__((address_space(3))) void*)l, 16, 0, 0);
}

// ---------------- f32 -> bf16 convert ----------------
__global__ __launch_bounds__(256) void cvt_f32_bf16_k(
    const float* __restrict__ in, unsigned short* __restrict__ out, int n4) {
  int i = blockIdx.x * 256 + threadIdx.x;
  if (i < n4) {
    float4 v = ((const float4*)in)[i];
    ushort4 o;
    o.x = f2bf(v.x); o.y = f2bf(v.y); o.z = f2bf(v.z); o.w = f2bf(v.w);
    ((ushort4*)out)[i] = o;
  }
}

// ---------------- weight transpose + convert: W[K,N] f32 -> Wt[N,K] bf16 ----
__global__ __launch_bounds__(256) void wtrans_k(
    const float* __restrict__ W, unsigned short* __restrict__ Wt) {
  __shared__ float tile[32][33];
  int n0 = blockIdx.x * 32, k0 = blockIdx.y * 32;
  int tx = threadIdx.x & 31, ty = threadIdx.x >> 5;
  #pragma unroll
  for (int i = 0; i < 32; i += 8)
    tile[ty + i][tx] = W[(size_t)(k0 + ty + i) * D_MODEL + n0 + tx];
  __syncthreads();
  #pragma unroll
  for (int i = 0; i < 32; i += 8)
    Wt[(size_t)(n0 + ty + i) * D_MODEL + k0 + tx] = f2bf(tile[tx][ty + i]);
}

// ---------------- bf16 GEMM 256x256 tile, 8 waves, phase-split K loop -------
// A[M,K] @ Bt[N,K]^T -> Cb[M,N] bf16 (+bias), + per-(row,64col) LN partials.
// LDS: [2 bufs][256 rows][64 k] per tensor, swizzled: (r,k) at
//   r*64 + ((k>>3 ^ (r&7))<<3) + (k&7)   (kills 16-way ds_read conflicts).
// Staging: LDS dest linear, inverse-XOR on per-lane global source.
// Per K-tile: 4 phases, each {8 ds_read_b128 | prefetch | 16 MFMA w/ setprio};
// one vmcnt(0)+lgkmcnt(0)+barrier per K-tile.
// grid: 1D 256 blocks = (M/256)*(N/256); XCD-swizzled (N==1024 -> 4 col tiles,
// row-panel's 4 col-tiles land on one XCD: xcd = p&7 = rb&7).
__global__ __launch_bounds__(512, 2) void gemm_bt_k(
    const unsigned short* __restrict__ A,
    const unsigned short* __restrict__ Bt,
    unsigned short* __restrict__ Cb,
    float* __restrict__ psum, float* __restrict__ psq,
    const float* __restrict__ bias,
    int M, int N, int K) {
  __shared__ unsigned short Al[2][256 * 64];
  __shared__ unsigned short Bl[2][256 * 64];
  int t = threadIdx.x;
  int lane = t & 63, wid = t >> 6;
  int wr = wid >> 2, wcn = wid & 3;        // 2 x 4 wave grid
  int l15 = lane & 15, lhi = lane >> 4;
  int p = blockIdx.x;
  int cb = (p >> 3) & 3;                   // col tile 0..3
  int rb = (p & 7) | ((p >> 5) << 3);      // row tile 0..63
  size_t m0 = (size_t)rb * 256, n0 = (size_t)cb * 256;
  f32x4 acc[8][4] = {};

  const int KT = K >> 6;                   // 16 K-tiles of 64
  // staging decode (linear LDS, inverse-swizzled source):
  // idx = sub*512 + t ; r = idx>>3 ; c_lds = idx&7 ; c_src = c_lds ^ (r&7)
  // prologue: stage K-tile 0 into buf 0
  #pragma unroll
  for (int sub = 0; sub < 4; ++sub) {
    int idx = sub * 512 + t;
    int r = idx >> 3, cl = idx & 7;
    int cg = cl ^ (r & 7);
    gload16(A  + (m0 + r) * (size_t)K + cg * 8, &Al[0][idx * 8]);
    gload16(Bt + (n0 + r) * (size_t)K + cg * 8, &Bl[0][idx * 8]);
  }
  asm volatile("s_waitcnt vmcnt(0)" ::: "memory");
  __builtin_amdgcn_s_barrier();
  __builtin_amdgcn_sched_barrier(0);

  for (int kt = 0; kt < KT; ++kt) {
    int cbuf = kt & 1;
    bool pf = (kt + 1) < KT;
    int k0n = (kt + 1) << 6;
    #pragma unroll
    for (int ph = 0; ph < 4; ++ph) {
      const int kk = ph >> 1, mh = ph & 1;
      if (pf && ph == 0) {
        #pragma unroll
        for (int sub = 0; sub < 4; ++sub) {
          int idx = sub * 512 + t;
          int r = idx >> 3, cl = idx & 7;
          int cg = cl ^ (r & 7);
          gload16(A + (m0 + r) * (size_t)K + k0n + cg * 8,
                  &Al[cbuf ^ 1][idx * 8]);
        }
        __builtin_amdgcn_sched_barrier(0);
      }
      if (pf && ph == 1) {
        #pragma unroll
        for (int sub = 0; sub < 4; ++sub) {
          int idx = sub * 512 + t;
          int r = idx >> 3, cl = idx & 7;
          int cg = cl ^ (r & 7);
          gload16(Bt + (n0 + r) * (size_t)K + k0n + cg * 8,
                  &Bl[cbuf ^ 1][idx * 8]);
        }
        __builtin_amdgcn_sched_barrier(0);
      }
      // fragment reads (swizzled): r&7 == l15&7 for all frag rows
      const int cx = (kk * 4 + lhi) ^ (l15 & 7);
      short8 af[4], bfr[4];
      #pragma unroll
      for (int m = 0; m < 4; ++m) {
        int r = wr * 128 + (mh * 4 + m) * 16 + l15;
        af[m] = *(const short8*)&Al[cbuf][r * 64 + cx * 8];
      }
      #pragma unroll
      for (int n = 0; n < 4; ++n) {
        int s = wcn * 64 + n * 16 + l15;
        bfr[n] = *(const short8*)&Bl[cbuf][s * 64 + cx * 8];
      }
      __builtin_amdgcn_s_setprio(1);
      #pragma unroll
      for (int m = 0; m < 4; ++m)
        #pragma unroll
        for (int n = 0; n < 4; ++n)
          acc[mh * 4 + m][n] = __builtin_amdgcn_mfma_f32_16x16x32_bf16(
              af[m], bfr[n], acc[mh * 4 + m][n], 0, 0, 0);
      __builtin_amdgcn_s_setprio(0);
    }
    asm volatile("s_waitcnt vmcnt(0) lgkmcnt(0)" ::: "memory");
    __builtin_amdgcn_s_barrier();
    __builtin_amdgcn_sched_barrier(0);
  }

  // bias into acc first (stats must include bias, like reference)
  if (bias) {
    float bv[4];
    #pragma unroll
    for (int n = 0; n < 4; ++n)
      bv[n] = bias[(int)n0 + wcn * 64 + n * 16 + l15];
    #pragma unroll
    for (int m = 0; m < 8; ++m)
      #pragma unroll
      for (int n = 0; n < 4; ++n)
        #pragma unroll
        for (int j = 0; j < 4; ++j)
          acc[m][n][j] += bv[n];
  }

  // per-row partial sum / sumsq over this wave's 64 cols
  int seg = (int)(n0 >> 6) + wcn;          // 0..15
  #pragma unroll
  for (int m = 0; m < 8; ++m) {
    float s[4], s2[4];
    #pragma unroll
    for (int j = 0; j < 4; ++j) {
      float a = 0.f, b = 0.f;
      #pragma unroll
      for (int n = 0; n < 4; ++n) {
        float x = acc[m][n][j];
        a += x; b += x * x;
      }
      s[j] = a; s2[j] = b;
    }
    #pragma unroll
    for (int off = 1; off < 16; off <<= 1) {
      #pragma unroll
      for (int j = 0; j < 4; ++j) {
        s[j]  += __shfl_xor(s[j],  off);
        s2[j] += __shfl_xor(s2[j], off);
      }
    }
    if (l15 == 0) {
      #pragma unroll
      for (int j = 0; j < 4; ++j) {
        int rg = (int)m0 + wr * 128 + m * 16 + lhi * 4 + j;
        psum[rg * 16 + seg] = s[j];
        psq [rg * 16 + seg] = s2[j];
      }
    }
  }

  // bf16 C write
  #pragma unroll
  for (int m = 0; m < 8; ++m)
    #pragma unroll
    for (int j = 0; j < 4; ++j) {
      size_t row = m0 + wr * 128 + m * 16 + lhi * 4 + j;
      #pragma unroll
      for (int n = 0; n < 4; ++n) {
        int col = (int)n0 + wcn * 64 + n * 16 + l15;
        Cb[row * N + col] = f2bf(acc[m][n][j]);
      }
    }
}

// ---------------- LN + activation from bf16 C + partials -> bf16 ------------
// mode 0: relu(ln)+eps ; mode 1: (relu(ln)+eps)*mask ; mode 2: ln*mask
__global__ __launch_bounds__(256) void ln_act_k(
    const unsigned short* __restrict__ Cb,
    const float* __restrict__ psum, const float* __restrict__ psq,
    const float* __restrict__ gamma, const float* __restrict__ beta,
    const float* __restrict__ mask,
    unsigned short* __restrict__ out, int mode) {
  int row = blockIdx.x;
  int t = threadIdx.x;
  float s = 0.f, s2 = 0.f;
  #pragma unroll
  for (int i = 0; i < 16; ++i) { s += psum[row * 16 + i]; s2 += psq[row * 16 + i]; }
  float mean = s * (1.f / D_MODEL);
  float var = s2 * (1.f / D_MODEL) - mean * mean;
  float rstd = rsqrtf(var + EPS_LN_F);
  float mk = (mode > 0) ? mask[row] : 1.f;
  ushort4 cv = ((const ushort4*)(Cb + (size_t)row * D_MODEL))[t];
  float4 gv = ((const float4*)gamma)[t];
  float4 bv = ((const float4*)beta)[t];
  float av[4] = {bf2f(cv.x), bf2f(cv.y), bf2f(cv.z), bf2f(cv.w)};
  float g4[4] = {gv.x, gv.y, gv.z, gv.w};
  float b4[4] = {bv.x, bv.y, bv.z, bv.w};
  unsigned short ov[4];
  #pragma unroll
  for (int j = 0; j < 4; ++j) {
    float ln = (av[j] - mean) * rstd * g4[j] + b4[j];
    if (mode == 0)      ln = fmaxf(ln, 0.f) + EPS_K_F;
    else if (mode == 1) ln = (fmaxf(ln, 0.f) + EPS_K_F) * mk;
    else                ln = ln * mk;
    ov[j] = f2bf(ln);
  }
  ushort4 o; o.x = ov[0]; o.y = ov[1]; o.z = ov[2]; o.w = ov[3];
  ((ushort4*)(out + (size_t)row * D_MODEL))[t] = o;
}

// ---------------- final LayerNorm from bf16 C + partials -> f32 out ---------
__global__ __launch_bounds__(256) void ln_final_k(
    const unsigned short* __restrict__ Cb,
    const float* __restrict__ psum, const float* __restrict__ psq,
    const float* __restrict__ gamma, const float* __restrict__ beta,
    float* __restrict__ out) {
  int row = blockIdx.x;
  int t = threadIdx.x;
  float s = 0.f, s2 = 0.f;
  #pragma unroll
  for (int i = 0; i < 16; ++i) { s += psum[row * 16 + i]; s2 += psq[row * 16 + i]; }
  float mean = s * (1.f / D_MODEL);
  float var = s2 * (1.f / D_MODEL) - mean * mean;
  float rstd = rsqrtf(var + EPS_LN_F);
  ushort4 cv = ((const ushort4*)(Cb + (size_t)row * D_MODEL))[t];
  float4 gv = ((const float4*)gamma)[t];
  float4 bv = ((const float4*)beta)[t];
  float4 w;
  w.x = (bf2f(cv.x) - mean) * rstd * gv.x + bv.x;
  w.y = (bf2f(cv.y) - mean) * rstd * gv.y + bv.y;
  w.z = (bf2f(cv.z) - mean) * rstd * gv.z + bv.z;
  w.w = (bf2f(cv.w) - mean) * rstd * gv.w + bv.w;
  ((float4*)(out + (size_t)row * D_MODEL))[t] = w;
}

// ---------------- KV via MFMA with swizzled-LDS transpose -------------------
__global__ __launch_bounds__(256) void kv_mfma_k(
    const unsigned short* __restrict__ Kp, const unsigned short* __restrict__ Vp,
    float* __restrict__ part, float* __restrict__ kspart) {
  __shared__ unsigned short Kl[4096];
  __shared__ unsigned short Vl[4096];
  int bh = blockIdx.y, chunk = blockIdx.x;   // chunk 0..7, 512 n each
  int b_ = bh >> 4, h = bh & 15;
  int t = threadIdx.x, lane = t & 63, w = t >> 6;
  int l15 = lane & 15, g = lane >> 4;        // g in 0..3

  int sn = t >> 2, sd16 = t & 3;
  int sc = sd16 ^ ((sn >> 3) & 3);
  size_t goff = (size_t)sn * D_MODEL + h * DEPTH + sd16 * 16;
  int ldst = sn * 64 + sc * 16;

  short8 ones;
  #pragma unroll
  for (int i = 0; i < 8; ++i) ones[i] = (short)0x3F80;

  f32x4 acc[4] = {};
  f32x4 ks = {};

  int baseA = ((w ^ g) << 4) + l15;
  int baseB0 = ((0 ^ g) << 4) + l15;
  int baseB1 = ((1 ^ g) << 4) + l15;
  int baseB2 = ((2 ^ g) << 4) + l15;
  int baseB3 = ((3 ^ g) << 4) + l15;

  size_t rowbase = ((size_t)b_ * S_LEN + (size_t)chunk * 512) * D_MODEL;
  for (int tile = 0; tile < 8; ++tile) {
    const unsigned short* kg = Kp + rowbase + (size_t)tile * 64 * D_MODEL + goff;
    const unsigned short* vg = Vp + rowbase + (size_t)tile * 64 * D_MODEL + goff;
    uint4 ra = *(const uint4*)kg;
    uint4 rb = *(const uint4*)(kg + 8);
    uint4 rc = *(const uint4*)vg;
    uint4 rd = *(const uint4*)(vg + 8);
    __syncthreads();
    *(uint4*)&Kl[ldst]     = ra;
    *(uint4*)&Kl[ldst + 8] = rb;
    *(uint4*)&Vl[ldst]     = rc;
    *(uint4*)&Vl[ldst + 8] = rd;
    __syncthreads();
    #pragma unroll
    for (int kk = 0; kk < 2; ++kk) {
      int nb = (kk * 32 + g * 8) * 64;
      short8 af, bf0, bf1, bf2, bf3;
      #pragma unroll
      for (int i = 0; i < 8; ++i) {
        int rowoff = nb + i * 64;
        af[i]  = (short)Kl[rowoff + baseA];
        bf0[i] = (short)Vl[rowoff + baseB0];
        bf1[i] = (short)Vl[rowoff + baseB1];
        bf2[i] = (short)Vl[rowoff + baseB2];
        bf3[i] = (short)Vl[rowoff + baseB3];
      }
      acc[0] = __builtin_amdgcn_mfma_f32_16x16x32_bf16(af, bf0, acc[0], 0, 0, 0);
      acc[1] = __builtin_amdgcn_mfma_f32_16x16x32_bf16(af, bf1, acc[1], 0, 0, 0);
      acc[2] = __builtin_amdgcn_mfma_f32_16x16x32_bf16(af, bf2, acc[2], 0, 0, 0);
      acc[3] = __builtin_amdgcn_mfma_f32_16x16x32_bf16(af, bf3, acc[3], 0, 0, 0);
      ks     = __builtin_amdgcn_mfma_f32_16x16x32_bf16(af, ones, ks, 0, 0, 0);
    }
  }
  float* pp = part + ((size_t)bh * 8 + chunk) * 4096;
  #pragma unroll
  for (int nf = 0; nf < 4; ++nf)
    #pragma unroll
    for (int r = 0; r < 4; ++r)
      pp[(16 * w + 4 * g + r) * 64 + 16 * nf + l15] = acc[nf][r];
  if (l15 == 0) {
    #pragma unroll
    for (int r = 0; r < 4; ++r)
      kspart[((size_t)bh * 8 + chunk) * 64 + 16 * w + 4 * g + r] = ks[r];
  }
}

// ---------------- KV reduce -> KV^T bf16 ([e][d]) + ksum f32 ----------------
__global__ __launch_bounds__(256) void kv_reduce_k(
    const float* __restrict__ part, const float* __restrict__ kspart,
    unsigned short* __restrict__ KVT, float* __restrict__ ksum) {
  int bh = blockIdx.x, t = threadIdx.x;
  for (int idx = t; idx < 4096; idx += 256) {
    int d = idx >> 6, e = idx & 63;
    float s = 0.f;
    #pragma unroll
    for (int c = 0; c < 8; ++c)
      s += part[((size_t)bh * 8 + c) * 4096 + d * 64 + e];
    KVT[(size_t)bh * 4096 + e * 64 + d] = f2bf(s);
  }
  if (t < 64) {
    float s = 0.f;
    #pragma unroll
    for (int c = 0; c < 8; ++c) s += kspart[((size_t)bh * 8 + c) * 64 + t];
    ksum[bh * 64 + t] = s;
  }
}

// ---------------- att = (q' @ KV) * z, written in the reference's reshape ---
__global__ __launch_bounds__(256) void att_k(
    const unsigned short* __restrict__ Qp, const unsigned short* __restrict__ KVT,
    const float* __restrict__ ksum, unsigned short* __restrict__ att) {
  __shared__ unsigned short Ql[128 * 64];
  __shared__ unsigned short Kl[64 * 64];
  __shared__ float ksl[64];
  __shared__ float zl[128];
  int bh = blockIdx.y;
  int b = bh >> 4, h = bh & 15;
  int r0 = blockIdx.x * 128;
  int t = threadIdx.x, lane = t & 63, wid = t >> 6;
  int l15 = lane & 15, lhi = lane >> 4;
  #pragma unroll
  for (int i = 0; i < 4; ++i) {
    int cid = i * 256 + t;
    int r = cid >> 3, c8 = cid & 7;
    gload16(Qp + ((size_t)(b * S_LEN + r0 + r)) * D_MODEL + h * DEPTH + c8 * 8,
            &Ql[cid * 8]);
  }
  #pragma unroll
  for (int i = 0; i < 2; ++i) {
    int cid = i * 256 + t;
    gload16(KVT + (size_t)bh * 4096 + cid * 8, &Kl[cid * 8]);
  }
  if (t < 64) ksl[t] = ksum[bh * 64 + t];
  asm volatile("s_waitcnt vmcnt(0)" ::: "memory");
  __syncthreads();
  {
    int r = t >> 1, half = t & 1;
    float s = 0.f;
    #pragma unroll
    for (int j = 0; j < 32; ++j)
      s += bf2f(Ql[r * 64 + half * 32 + j]) * ksl[half * 32 + j];
    s += __shfl_xor(s, 1);
    if (half == 0) zl[r] = 1.f / (s + EPS_K_F);
  }
  __syncthreads();
  f32x4 acc[2][4] = {};
  #pragma unroll
  for (int kk = 0; kk < 2; ++kk) {
    short8 af[2], bfr[4];
    #pragma unroll
    for (int m = 0; m < 2; ++m)
      af[m] = *(const short8*)&Ql[(wid * 32 + m * 16 + l15) * 64 + kk * 32 + lhi * 8];
    #pragma unroll
    for (int n = 0; n < 4; ++n)
      bfr[n] = *(const short8*)&Kl[(n * 16 + l15) * 64 + kk * 32 + lhi * 8];
    #pragma unroll
    for (int m = 0; m < 2; ++m)
      #pragma unroll
      for (int n = 0; n < 4; ++n)
        acc[m][n] = __builtin_amdgcn_mfma_f32_16x16x32_bf16(af[m], bfr[n], acc[m][n], 0, 0, 0);
  }
  #pragma unroll
  for (int m = 0; m < 2; ++m)
    #pragma unroll
    for (int j = 0; j < 4; ++j) {
      int rl = wid * 32 + m * 16 + lhi * 4 + j;
      int n = r0 + rl;
      float z = zl[rl];
      #pragma unroll
      for (int nf = 0; nf < 4; ++nf) {
        int ee = nf * 16 + l15;
        size_t orow = (size_t)b * S_LEN + h * 256 + (n >> 4);
        int ocol = (n & 15) * 64 + ee;
        att[orow * D_MODEL + ocol] = f2bf(acc[m][nf][j] * z);
      }
    }
}

extern "C" void kernel_launch(void* const* d_in, const int* in_sizes, int n_in,
                              void* d_out, int out_size, void* d_ws, size_t ws_size,
                              hipStream_t stream) {
  (void)in_sizes; (void)n_in; (void)out_size; (void)ws_size;
  const float* q     = (const float*)d_in[0];
  const float* k     = (const float*)d_in[1];
  const float* v     = (const float*)d_in[2];
  const float* mask  = (const float*)d_in[3];
  const float* wq    = (const float*)d_in[4];
  const float* wk    = (const float*)d_in[5];
  const float* wv    = (const float*)d_in[6];
  const float* gamma = (const float*)d_in[7];
  const float* beta  = (const float*)d_in[8];
  const float* dw    = (const float*)d_in[9];
  const float* db    = (const float*)d_in[10];
  float* out = (float*)d_out;

  char* ws = (char*)d_ws;
  unsigned short* Xb  = (unsigned short*)(ws);               // 33.5 MB
  unsigned short* Qp  = (unsigned short*)(ws + 33554432);    // also dense-C after att
  unsigned short* Kp  = (unsigned short*)(ws + 67108864);
  unsigned short* Vp  = (unsigned short*)(ws + 100663296);
  unsigned short* WqT = (unsigned short*)(ws + 134217728);
  unsigned short* WkT = WqT + 1048576;
  unsigned short* WvT = WkT + 1048576;
  unsigned short* WdT = WvT + 1048576;
  float* part   = (float*)(ws);             // aliases Xb (dead mid-pipeline)
  float* kspart = (float*)(ws + 8388608);
  unsigned short* KVT = (unsigned short*)(ws + 142606336);
  float* ksum = (float*)(ws + 143130624);
  float* psum = (float*)(ws + 143654912);   // 16384*16 f32 = 1 MB
  float* psq  = (float*)(ws + 144703488);   // 1 MB
  unsigned short* Cqkv = (unsigned short*)d_out;   // bf16 C scratch (32 MB of 67)
  unsigned short* Cd   = Qp;                       // dense C: Qp dead after att_k

  dim3 b256(256);
  dim3 b512(512);
  int n4 = ROWS * D_MODEL / 4;
  dim3 cvtg(n4 / 256);
  dim3 wtg(32, 32);
  dim3 gemmg(256);            // (M/256)*(N/256), XCD-swizzled in-kernel
  dim3 lng(ROWS);

  wtrans_k<<<wtg, b256, 0, stream>>>(wq, WqT);
  wtrans_k<<<wtg, b256, 0, stream>>>(wk, WkT);
  wtrans_k<<<wtg, b256, 0, stream>>>(wv, WvT);
  wtrans_k<<<wtg, b256, 0, stream>>>(dw, WdT);

  cvt_f32_bf16_k<<<cvtg, b256, 0, stream>>>(q, Xb, n4);
  gemm_bt_k<<<gemmg, b512, 0, stream>>>(Xb, WqT, Cqkv, psum, psq, nullptr, ROWS, D_MODEL, D_MODEL);
  ln_act_k<<<lng, b256, 0, stream>>>(Cqkv, psum, psq, gamma, beta, nullptr, Qp, 0);

  cvt_f32_bf16_k<<<cvtg, b256, 0, stream>>>(k, Xb, n4);
  gemm_bt_k<<<gemmg, b512, 0, stream>>>(Xb, WkT, Cqkv, psum, psq, nullptr, ROWS, D_MODEL, D_MODEL);
  ln_act_k<<<lng, b256, 0, stream>>>(Cqkv, psum, psq, gamma, beta, mask, Kp, 1);

  cvt_f32_bf16_k<<<cvtg, b256, 0, stream>>>(v, Xb, n4);
  gemm_bt_k<<<gemmg, b512, 0, stream>>>(Xb, WvT, Cqkv, psum, psq, nullptr, ROWS, D_MODEL, D_MODEL);
  ln_act_k<<<lng, b256, 0, stream>>>(Cqkv, psum, psq, gamma, beta, mask, Vp, 2);

  kv_mfma_k<<<dim3(8, 64), b256, 0, stream>>>(Kp, Vp, part, kspart);
  kv_reduce_k<<<dim3(64), b256, 0, stream>>>(part, kspart, KVT, ksum);
  att_k<<<dim3(32, 64), b256, 0, stream>>>(Qp, KVT, ksum, Xb);

  gemm_bt_k<<<gemmg, b512, 0, stream>>>(Xb, WdT, Cd, psum, psq, db, ROWS, D_MODEL, D_MODEL);
  ln_final_k<<<lng, b256, 0, stream>>>(Cd, psum, psq, gamma, beta, out);
}